// Round 8
// baseline (36.839 us; speedup 1.0000x reference)
//
#include <hip/hip_runtime.h>
#include <hip/hip_bf16.h>

// LDPC normalized min-sum decoder, B=8, M=1024 checks, N=2048 vars.
// Round 7 -> 8: rows are partitioned by degree in build_rows (deg==8 rows,
// ~96%, get ids 0..n8-1 via global atomic counter; higher-degree rows pack
// at the top). Decode branches wave-uniformly: deg-8 waves run a fixed
// 8-slot body with no predication (18 LDS issues/iter vs 26), tail wave
// keeps the MAXD-predicated body. Row permutation is legal (output is
// column-indexed) and output stays bitwise deterministic (integer column
// adds are commutative). Keep: peeled iteration 0, named accumulator
// rotation, dead-reset elimination, Q14 ds_add_u32 column accumulation.

#define M_CHECK 1024
#define N_VAR   2048
#define BATCH   8
#define MAXD    12               // max supported row degree (actual <= ~10)
#define NUM_ITERS 5
#define FXS 16384.0f             // Q14 fixed-point scale
#define FXI (1.0f / 16384.0f)

// ---------------------------------------------------------------------------
// Kernel A: wave-per-row ordered compaction of dense H. Row m's columns are
// staged in LDS, then the row is assigned a new id by degree class:
//   deg==8 -> cnt[0]++ (ids from 0 upward), deg>8 -> cnt[1]++ (ids from 1023
// downward). deg/row_cols_T are stored at the new id (column-major).
__global__ __launch_bounds__(256) void build_rows_kernel(
    const int* __restrict__ H, int* __restrict__ cnt,
    int* __restrict__ deg, int* __restrict__ row_cols_T)
{
    __shared__ int stage[4][MAXD];
    __shared__ int info[4][2];                 // {new_id, clamped_deg} per wave

    const int w    = threadIdx.x >> 6;         // wave within block (4 rows/blk)
    const int lane = threadIdx.x & 63;
    const int m    = blockIdx.x * 4 + w;
    const unsigned long long below = (1ULL << lane) - 1ULL;
    const int4* __restrict__ H4 = (const int4*)(H + m * N_VAR);

    int base = 0;
    for (int c = 0; c < N_VAR; c += 256) {     // 256 cols per pass
        int4 h = H4[(c >> 2) + lane];
        unsigned long long m0 = __ballot(h.x != 0);
        unsigned long long m1 = __ballot(h.y != 0);
        unsigned long long m2 = __ballot(h.z != 0);
        unsigned long long m3 = __ballot(h.w != 0);
        int pb = __popcll(m0 & below) + __popcll(m1 & below)
               + __popcll(m2 & below) + __popcll(m3 & below);
        int b0 = (int)((m0 >> lane) & 1);
        int b1 = (int)((m1 >> lane) & 1);
        int b2 = (int)((m2 >> lane) & 1);
        int col = c + 4 * lane;
        int r = base + pb;
        if (h.x) { if (r < MAXD) stage[w][r] = col; }
        r += b0;
        if (h.y) { if (r < MAXD) stage[w][r] = col + 1; }
        r += b1;
        if (h.z) { if (r < MAXD) stage[w][r] = col + 2; }
        r += b2;
        if (h.w) { if (r < MAXD) stage[w][r] = col + 3; }
        base += __popcll(m0) + __popcll(m1) + __popcll(m2) + __popcll(m3);
    }

    if (lane == 0) {
        int degc = (base < MAXD) ? base : MAXD;
        int is8  = (degc == 8) ? 1 : 0;
        int pos  = atomicAdd(&cnt[is8 ? 0 : 1], 1);
        int nid  = is8 ? pos : (M_CHECK - 1 - pos);
        deg[nid] = degc;
        info[w][0] = nid;
        info[w][1] = degc;
    }
    __syncthreads();

    const int nid  = info[w][0];
    const int degc = info[w][1];
    if (lane < degc)
        row_cols_T[lane * M_CHECK + nid] = stage[w][lane];
}

// ---------------------------------------------------------------------------
// One row-phase body. DLIM: unroll extent. PRED: predicate slots on d<dm.
// PEEL: iteration 0 (cv=0, acc=0 -> vc = softc, no gather).
#define ROW_BODY(DLIM, PRED, ACCG, ACCS, PEEL)                               \
  {                                                                          \
    float vcs[MAXD];                                                         \
    float mn1 = 1e38f, mn2 = 1e38f;                                          \
    unsigned sx = 0u; bool zr = false;                                       \
    _Pragma("unroll")                                                        \
    for (int d = 0; d < DLIM; ++d) {                                         \
      if (!PRED || d < dm) {                                                 \
        float vc = PEEL ? softc[d]                                           \
                        : softc[d] + (float)ACCG[cols[d]] * FXI - cv[d];     \
        vcs[d] = vc;                                                         \
        float a = fabsf(vc);                                                 \
        if (a < mn1) { mn2 = mn1; mn1 = a; }                                 \
        else if (a < mn2) { mn2 = a; }                                       \
        sx ^= (__float_as_uint(vc) & 0x80000000u);                           \
        zr |= (vc == 0.f);                                                   \
      }                                                                      \
    }                                                                        \
    const float zmul = zr ? 0.f : alpha;                                     \
    _Pragma("unroll")                                                        \
    for (int d = 0; d < DLIM; ++d) {                                         \
      if (!PRED || d < dm) {                                                 \
        float vc  = vcs[d];                                                  \
        float a   = fabsf(vc);                                               \
        float res = (a > mn1) ? mn1 : mn2;      /* exclude-self min */       \
        unsigned o = sx ^ (__float_as_uint(vc) & 0x80000000u);               \
        float v   = res * zmul;                 /* >= 0 */                   \
        float cvn = __uint_as_float(__float_as_uint(v) ^ o);                 \
        cv[d] = cvn;                                                         \
        atomicAdd(&ACCS[cols[d]], __float2int_rn(cvn * FXS));                \
      }                                                                      \
    }                                                                        \
  }

// One full iteration: wave-uniform branch between deg-8 and predicated body,
// optional accumulator reset, one barrier.
#define DECODE_ITER(ACCG, ACCS, PEEL, DO_RESET, ACCR)                        \
  if (clean) ROW_BODY(8,    false, ACCG, ACCS, PEEL)                         \
  else       ROW_BODY(MAXD, true,  ACCG, ACCS, PEEL)                         \
  if (DO_RESET) { ACCR[n0] = 0; ACCR[n1] = 0; }                              \
  __syncthreads();

// ---------------------------------------------------------------------------
// Kernel B: full decode, one block per batch, 1024 threads, 1 row/thread.
__global__ __launch_bounds__(1024) void decode_kernel(
    const float* __restrict__ soft_input, const float* __restrict__ check_weight,
    const int* __restrict__ cnt, const int* __restrict__ deg,
    const int* __restrict__ row_cols_T, float* __restrict__ out)
{
    __shared__ int   acc0[N_VAR];      // 8 KB each
    __shared__ int   acc1[N_VAR];
    __shared__ int   acc2[N_VAR];
    __shared__ float soft_s[N_VAR];

    const int b = blockIdx.x;
    const int t = threadIdx.x;
    const float alpha = log1pf(expf(check_weight[0]));   // softplus(w)

    const int n0 = t, n1 = t + 1024;
    const float s0 = soft_input[b * N_VAR + n0];
    const float s1 = soft_input[b * N_VAR + n1];
    soft_s[n0] = s0;  soft_s[n1] = s1;
    acc1[n0] = 0; acc1[n1] = 0;        // peel scatters into acc1
    acc2[n0] = 0; acc2[n1] = 0;        // it=1 scatters into acc2
    // acc0: reset at it=1, first scattered at it=2 — no init needed.

    const int n8 = cnt[0];                     // count of deg-8 rows
    const bool clean = ((t | 63) < n8);        // wave-uniform: whole wave deg-8

    const int dm = deg[t];
    int cols[MAXD];
#pragma unroll
    for (int d = 0; d < MAXD; ++d)
        cols[d] = (d < dm) ? row_cols_T[d * M_CHECK + t] : 0;   // coalesced
    __syncthreads();

    // per-edge soft inputs (registers; one-time LDS gather)
    float softc[MAXD];
#pragma unroll
    for (int d = 0; d < MAXD; ++d)
        softc[d] = (d < dm) ? soft_s[cols[d]] : 0.f;

    float cv[MAXD];

    // it=0 (peeled, no gather)         G     S    PEEL  RESET ACCR
    DECODE_ITER(acc0, acc1,                  true,  false, acc0)
    DECODE_ITER(acc1, acc2,                  false, true,  acc0)   // it=1
    DECODE_ITER(acc2, acc0,                  false, true,  acc1)   // it=2
    DECODE_ITER(acc0, acc1,                  false, true,  acc2)   // it=3
    DECODE_ITER(acc1, acc2,                  false, false, acc0)   // it=4

    // posterior LLRs from the last scatter buffer (acc2)
    out[b * N_VAR + n0] = s0 + (float)acc2[n0] * FXI;
    out[b * N_VAR + n1] = s1 + (float)acc2[n1] * FXI;
}

// ---------------------------------------------------------------------------
extern "C" void kernel_launch(void* const* d_in, const int* in_sizes, int n_in,
                              void* d_out, int out_size, void* d_ws, size_t ws_size,
                              hipStream_t stream)
{
    const float* soft_input   = (const float*)d_in[0];
    const float* check_weight = (const float*)d_in[1];
    const int*   H            = (const int*)d_in[2];
    float*       out          = (float*)d_out;

    int* cnt        = (int*)d_ws;                  // 2 counters (+2 pad)
    int* deg        = cnt + 4;                     // M
    int* row_cols_T = deg + M_CHECK;               // MAXD * M (col-major)

    hipMemsetAsync(cnt, 0, 2 * sizeof(int), stream);
    build_rows_kernel<<<M_CHECK / 4, 256, 0, stream>>>(H, cnt, deg, row_cols_T);
    decode_kernel<<<BATCH, 1024, 0, stream>>>(
        soft_input, check_weight, cnt, deg, row_cols_T, out);
}

// Round 9
// 21.481 us; speedup vs baseline: 1.7149x; 1.7149x over previous
//
#include <hip/hip_runtime.h>
#include <hip/hip_bf16.h>

// LDPC normalized min-sum decoder, B=8, M=1024 checks, N=2048 vars.
// Round 8 -> 9: drop the hipMemsetAsync (graph-captured 8-byte fill cost
// ~15us — it profiled like a full blit). Degree partition is now computed
// deterministically INSIDE decode: ballot/popcount rank + 16-entry wave-count
// prefix -> permutation (clean deg-8 rows to ids 0..n8-1, dirty rows to the
// top), scattered through acc0. 15/16 waves then run a fixed 8-slot body
// with no predication (18 LDS issues/iter vs 26). Output stays bitwise
// deterministic: permutation is a pure function of deg[], and Q14 integer
// column adds are commutative.

#define M_CHECK 1024
#define N_VAR   2048
#define BATCH   8
#define MAXD    12               // max supported row degree (actual <= ~10)
#define NUM_ITERS 5
#define FXS 16384.0f             // Q14 fixed-point scale
#define FXI (1.0f / 16384.0f)

// ---------------------------------------------------------------------------
// Kernel A: wave-per-row ordered compaction of dense H -> deg, row_cols_T
// (column-major [MAXD][M], original row ids). int4-vectorized, deterministic
// ballot/popcount ranking. (Round-7 version — no counters, no staging.)
__global__ __launch_bounds__(256) void build_rows_kernel(
    const int* __restrict__ H, int* __restrict__ deg,
    int* __restrict__ row_cols_T)
{
    const int m    = blockIdx.x * 4 + (threadIdx.x >> 6);   // wave per row
    const int lane = threadIdx.x & 63;
    const unsigned long long below = (1ULL << lane) - 1ULL;
    const int4* __restrict__ H4 = (const int4*)(H + m * N_VAR);

    int base = 0;
    for (int c = 0; c < N_VAR; c += 256) {                  // 256 cols per pass
        int4 h = H4[(c >> 2) + lane];
        unsigned long long m0 = __ballot(h.x != 0);
        unsigned long long m1 = __ballot(h.y != 0);
        unsigned long long m2 = __ballot(h.z != 0);
        unsigned long long m3 = __ballot(h.w != 0);
        int pb = __popcll(m0 & below) + __popcll(m1 & below)
               + __popcll(m2 & below) + __popcll(m3 & below);
        int b0 = (int)((m0 >> lane) & 1);
        int b1 = (int)((m1 >> lane) & 1);
        int b2 = (int)((m2 >> lane) & 1);
        int col = c + 4 * lane;
        int r = base + pb;
        if (h.x) { if (r < MAXD) row_cols_T[r * M_CHECK + m] = col; }
        r += b0;
        if (h.y) { if (r < MAXD) row_cols_T[r * M_CHECK + m] = col + 1; }
        r += b1;
        if (h.z) { if (r < MAXD) row_cols_T[r * M_CHECK + m] = col + 2; }
        r += b2;
        if (h.w) { if (r < MAXD) row_cols_T[r * M_CHECK + m] = col + 3; }
        base += __popcll(m0) + __popcll(m1) + __popcll(m2) + __popcll(m3);
    }
    if (lane == 0) deg[m] = (base < MAXD) ? base : MAXD;
}

// ---------------------------------------------------------------------------
// One row-phase body. DLIM: unroll extent. PRED: predicate slots on d<dm.
// PEEL (compile-time): iteration 0 (cv=0, acc=0 -> vc = softc, no gather).
#define ROW_BODY(DLIM, PRED, ACCG, ACCS, PEEL)                               \
  {                                                                          \
    float vcs[MAXD];                                                         \
    float mn1 = 1e38f, mn2 = 1e38f;                                          \
    unsigned sx = 0u; bool zr = false;                                       \
    _Pragma("unroll")                                                        \
    for (int d = 0; d < DLIM; ++d) {                                         \
      if (!PRED || d < dm) {                                                 \
        float vc = PEEL ? softc[d]                                           \
                        : softc[d] + (float)ACCG[cols[d]] * FXI - cv[d];     \
        vcs[d] = vc;                                                         \
        float a = fabsf(vc);                                                 \
        if (a < mn1) { mn2 = mn1; mn1 = a; }                                 \
        else if (a < mn2) { mn2 = a; }                                       \
        sx ^= (__float_as_uint(vc) & 0x80000000u);                           \
        zr |= (vc == 0.f);                                                   \
      }                                                                      \
    }                                                                        \
    const float zmul = zr ? 0.f : alpha;                                     \
    _Pragma("unroll")                                                        \
    for (int d = 0; d < DLIM; ++d) {                                         \
      if (!PRED || d < dm) {                                                 \
        float vc  = vcs[d];                                                  \
        float a   = fabsf(vc);                                               \
        float res = (a > mn1) ? mn1 : mn2;      /* exclude-self min */       \
        unsigned o = sx ^ (__float_as_uint(vc) & 0x80000000u);               \
        float v   = res * zmul;                 /* >= 0 */                   \
        float cvn = __uint_as_float(__float_as_uint(v) ^ o);                 \
        cv[d] = cvn;                                                         \
        atomicAdd(&ACCS[cols[d]], __float2int_rn(cvn * FXS));                \
      }                                                                      \
    }                                                                        \
  }

// One full iteration: wave-uniform branch between the fixed deg-8 body and
// the MAXD-predicated body, optional accumulator reset, one barrier.
#define DECODE_ITER(ACCG, ACCS, PEEL, DO_RESET, ACCR)                        \
  if (clean) ROW_BODY(8,    false, ACCG, ACCS, PEEL)                         \
  else       ROW_BODY(MAXD, true,  ACCG, ACCS, PEEL)                         \
  if (DO_RESET) { ACCR[n0] = 0; ACCR[n1] = 0; }                              \
  __syncthreads();

// ---------------------------------------------------------------------------
// Kernel B: full decode, one block per batch, 1024 threads, 1 row/thread.
// cv in registers; column sums via Q14 integer LDS atomics (native
// ds_add_u32, commutative -> deterministic) into 3 rotating accumulators.
__global__ __launch_bounds__(1024) void decode_kernel(
    const float* __restrict__ soft_input, const float* __restrict__ check_weight,
    const int* __restrict__ deg, const int* __restrict__ row_cols_T,
    float* __restrict__ out)
{
    __shared__ int   acc0[N_VAR];      // 8 KB each; acc0 doubles as rowperm
    __shared__ int   acc1[N_VAR];
    __shared__ int   acc2[N_VAR];
    __shared__ float soft_s[N_VAR];
    __shared__ int   wc[16];           // per-wave dirty counts

    const int b = blockIdx.x;
    const int t = threadIdx.x;
    const float alpha = log1pf(expf(check_weight[0]));   // softplus(w)

    const int n0 = t, n1 = t + 1024;
    const float s0 = soft_input[b * N_VAR + n0];
    const float s1 = soft_input[b * N_VAR + n1];
    soft_s[n0] = s0;  soft_s[n1] = s1;
    acc1[n0] = 0; acc1[n1] = 0;        // peel scatters into acc1
    acc2[n0] = 0; acc2[n1] = 0;        // it=1 scatters into acc2
    // acc0: holds rowperm now; reset at it=1, first gathered at it=2.

    // ---- deterministic degree partition (pure function of deg[])
    const int  dmo   = deg[t];
    const bool dirty = (dmo != 8);
    const int  lane  = t & 63, w = t >> 6;
    unsigned long long dmask = __ballot(dirty);
    const int rnk = __popcll(dmask & ((1ULL << lane) - 1ULL));
    if (lane == 0) wc[w] = __popcll(dmask);
    __syncthreads();                                   // barrier A

    int totd = 0, pref = 0;
#pragma unroll
    for (int i = 0; i < 16; ++i) {
        int c = wc[i];
        totd += c;
        if (i < w) pref += c;
    }
    const int n8 = M_CHECK - totd;                     // count of deg-8 rows
    const int db = pref + rnk;                         // dirty rows before t
    const int new_id = dirty ? (n8 + db) : (t - db);
    acc0[new_id] = t;                                  // rowperm scatter
    __syncthreads();                                   // barrier B

    const int  orig  = acc0[t];                        // row this thread runs
    const int  dm    = deg[orig];
    const bool clean = ((t | 63) < n8);                // whole wave deg-8

    int cols[MAXD];
#pragma unroll
    for (int d = 0; d < MAXD; ++d)
        cols[d] = (d < dm) ? row_cols_T[d * M_CHECK + orig] : 0;

    // per-edge soft inputs (registers; soft_s visible since barrier A)
    float softc[MAXD];
#pragma unroll
    for (int d = 0; d < MAXD; ++d)
        softc[d] = (d < dm) ? soft_s[cols[d]] : 0.f;

    float cv[MAXD];

    //           G     S     PEEL   RESET  ACCR
    DECODE_ITER(acc0, acc1,  true,  false, acc0)   // it=0 (no gather)
    DECODE_ITER(acc1, acc2,  false, true,  acc0)   // it=1 (clears rowperm)
    DECODE_ITER(acc2, acc0,  false, true,  acc1)   // it=2
    DECODE_ITER(acc0, acc1,  false, true,  acc2)   // it=3
    DECODE_ITER(acc1, acc2,  false, false, acc0)   // it=4 (reset dead)

    // ---- posterior LLRs from the last scatter buffer (acc2)
    out[b * N_VAR + n0] = s0 + (float)acc2[n0] * FXI;
    out[b * N_VAR + n1] = s1 + (float)acc2[n1] * FXI;
}

// ---------------------------------------------------------------------------
extern "C" void kernel_launch(void* const* d_in, const int* in_sizes, int n_in,
                              void* d_out, int out_size, void* d_ws, size_t ws_size,
                              hipStream_t stream)
{
    const float* soft_input   = (const float*)d_in[0];
    const float* check_weight = (const float*)d_in[1];
    const int*   H            = (const int*)d_in[2];
    float*       out          = (float*)d_out;

    int* deg        = (int*)d_ws;                  // M
    int* row_cols_T = deg + M_CHECK;               // MAXD * M (col-major)

    build_rows_kernel<<<M_CHECK / 4, 256, 0, stream>>>(H, deg, row_cols_T);
    decode_kernel<<<BATCH, 1024, 0, stream>>>(
        soft_input, check_weight, deg, row_cols_T, out);
}